// Round 9
// baseline (520.287 us; speedup 1.0000x reference)
//
#include <hip/hip_runtime.h>
#include <math.h>

// Problem constants
#define NSAMP 220500
#define NCH   28
#define HPCH  24
#define TILE  2048
#define BLOCK 256

// Tap geometry
#define LP_GT4 4032   // h4 stride (3997 actual)
#define L_H4F  4252   // src_fwd (*) h4 combined length
#define LP_H4F 4288   // h4f stride
#define LP_HP  1008
#define LP_ENV 2016
#define L_TB   388    // lpf (*) src_bwd
#define LP_TB  432

// K-step counts
#define NC_GT 134     // 16x16x32 desc (r8-proven mapping)
#define NC_HP 65      // 32x32x16 desc
#define NC_EF 128     // 32x32x16 desc
#define NC_EB 128     // 32x32x16 asc

typedef __attribute__((ext_vector_type(4)))  float f32x4;
typedef __attribute__((ext_vector_type(16))) float f32x16;
typedef __attribute__((ext_vector_type(8)))  short bf16x8;

__device__ __forceinline__ int phys9(int u) { return u + (u >> 3); }

__device__ __forceinline__ unsigned short f2bf(float x) {
    unsigned u = __float_as_uint(x);
    u += 0x7FFFu + ((u >> 16) & 1u);
    return (unsigned short)(u >> 16);
}

#define MFMA16 __builtin_amdgcn_mfma_f32_16x16x32_bf16
#define MFMA32 __builtin_amdgcn_mfma_f32_32x32x16_bf16

// ===========================================================================
// gt4 tap prep: step-major layout TF2[g][s][pc][512], pc = plane*4 + cc.
// A_s[m][kap] = h4f[c][32s + m - 1 - kap] (r8-proven); elem i of lane l =
// A[l&15][8*(l>>4)+i]. hi plane pc=cc, lo plane pc=4+cc.
// ===========================================================================
__global__ void prep_gt(const float* __restrict__ h4f, unsigned short* __restrict__ TF2)
{
    const int s  = blockIdx.x;
    const int ch = blockIdx.y;
    const int g  = ch >> 2, cc = ch & 3;
    const int l  = threadIdx.x;           // 64 threads
    const int m  = l & 15, hib = (l >> 4) * 8;
    unsigned short* base = TF2 + ((size_t)g * NC_GT + s) * 8192 + cc * 512 + l * 8;
#pragma unroll
    for (int i = 0; i < 8; i++) {
        int kap = hib + i;
        int k = 32 * s + m - 1 - kap;
        float val = (k >= 0 && k < LP_H4F) ? h4f[(size_t)ch * LP_H4F + k] : 0.f;
        unsigned short hh = f2bf(val);
        base[i] = hh;
        float fh = __uint_as_float((unsigned)hh << 16);
        base[2048 + i] = f2bf(val - fh);   // lo plane at +4 frags
    }
}

// 32x32x16 tap prep (r8-proven mappings)
__global__ void prep_frag32(const float* __restrict__ taps, int pitch,
                            unsigned short* __restrict__ TF, int NC, int isAsc)
{
    const int s  = blockIdx.x;
    const int ch = blockIdx.y;
    const int l  = threadIdx.x;
    const int m  = l & 31, kb = (l >> 5) * 8;
    unsigned short* dst = TF + ((size_t)ch * NC + s) * 512 + l * 8;
#pragma unroll
    for (int i = 0; i < 8; i++) {
        int kap = kb + i;
        int k = isAsc ? (16 * s + kap - m) : (16 * s + m - 17 - kap);
        float val = (k >= 0 && k < pitch) ? taps[(size_t)ch * pitch + k] : 0.f;
        dst[i] = f2bf(val);
    }
}

// ===========================================================================
// gt4 v3: 4 channels/block share one staged window; step-major taps with
// immediate-offset loads; b128 B-reads via P32 swizzle (pad 4 per 32 dwords:
// 8-dword lane stride -> <=2-way banks, 16B-aligned); next-B prefetch.
// B dword v = 256w + 8n + 4hib + 16(NC-1) - 16s; tile2 at +128 dwords
// (phys +144); samples at dword v are (o+2v, o+2v+1), o = jb-4255.
// ===========================================================================
#define GTDW 3160
__global__ __launch_bounds__(BLOCK)
void gt4_v3(const float* __restrict__ x, const unsigned short* __restrict__ TF2,
            float* __restrict__ out)
{
    extern __shared__ float S[];
    unsigned* S32 = (unsigned*)S;
    const int jb = blockIdx.x * 2048;
    const int g  = blockIdx.y;
    const int o  = jb - 4255;

    for (int v = threadIdx.x; v < GTDW; v += BLOCK) {
        int p0 = o + 2 * v, p1 = p0 + 1;
        float a = (p0 >= 0 && p0 < NSAMP) ? x[p0] : 0.f;
        float b = (p1 >= 0 && p1 < NSAMP) ? x[p1] : 0.f;
        S32[32 + v + ((v >> 5) << 2)] = (unsigned)f2bf(a) | ((unsigned)f2bf(b) << 16);
    }
    __syncthreads();

    const int lane = threadIdx.x & 63;
    const int w    = threadIdx.x >> 6;
    const int n    = lane & 15;
    const int hib  = lane >> 4;
    int v = 256 * w + 8 * n + 4 * hib + 16 * (NC_GT - 1);

    const unsigned short* tpA = TF2 + (size_t)g * NC_GT * 8192 + lane * 8; // hi cc0..3
    const unsigned short* tpB = tpA + 2048;                                // lo cc0..3

    f32x4 a00={0,0,0,0}, a01={0,0,0,0}, a10={0,0,0,0}, a11={0,0,0,0};
    f32x4 a20={0,0,0,0}, a21={0,0,0,0}, a30={0,0,0,0}, a31={0,0,0,0};

    union Ub { f32x4 f; bf16x8 v; };
    int vp = 32 + v + ((v >> 5) << 2);
    Ub B0, B1;
    B0.f = *(const f32x4*)(S + vp);
    B1.f = *(const f32x4*)(S + vp + 144);

#pragma unroll 1
    for (int s = 0; s < NC_GT; ++s) {
        bf16x8 h0 = *(const bf16x8*)(tpA);
        bf16x8 h1 = *(const bf16x8*)(tpA + 512);
        bf16x8 h2 = *(const bf16x8*)(tpA + 1024);
        bf16x8 h3 = *(const bf16x8*)(tpA + 1536);
        bf16x8 l0 = *(const bf16x8*)(tpB);
        bf16x8 l1 = *(const bf16x8*)(tpB + 512);
        bf16x8 l2 = *(const bf16x8*)(tpB + 1024);
        bf16x8 l3 = *(const bf16x8*)(tpB + 1536);
        v -= 16;
        vp = 32 + v + ((v >> 5) << 2);       // guard region absorbs final v=-16
        Ub N0, N1;
        N0.f = *(const f32x4*)(S + vp);
        N1.f = *(const f32x4*)(S + vp + 144);

        a00 = MFMA16(h0, B0.v, a00,0,0,0);  a00 = MFMA16(l0, B0.v, a00,0,0,0);
        a10 = MFMA16(h1, B0.v, a10,0,0,0);  a10 = MFMA16(l1, B0.v, a10,0,0,0);
        a20 = MFMA16(h2, B0.v, a20,0,0,0);  a20 = MFMA16(l2, B0.v, a20,0,0,0);
        a30 = MFMA16(h3, B0.v, a30,0,0,0);  a30 = MFMA16(l3, B0.v, a30,0,0,0);
        a01 = MFMA16(h0, B1.v, a01,0,0,0);  a01 = MFMA16(l0, B1.v, a01,0,0,0);
        a11 = MFMA16(h1, B1.v, a11,0,0,0);  a11 = MFMA16(l1, B1.v, a11,0,0,0);
        a21 = MFMA16(h2, B1.v, a21,0,0,0);  a21 = MFMA16(l2, B1.v, a21,0,0,0);
        a31 = MFMA16(h3, B1.v, a31,0,0,0);  a31 = MFMA16(l3, B1.v, a31,0,0,0);

        B0 = N0; B1 = N1;
        tpA += 8192; tpB += 8192;
    }

    const int c0 = 4 * g;
    const int j0 = jb + 512 * w + 16 * n + 4 * hib;
    float* y0 = out + (size_t)(c0 + 0) * NSAMP;
    float* y1 = out + (size_t)(c0 + 1) * NSAMP;
    float* y2 = out + (size_t)(c0 + 2) * NSAMP;
    float* y3 = out + (size_t)(c0 + 3) * NSAMP;
    if (j0 < NSAMP) {
        *(f32x4*)(y0 + j0) = a00; *(f32x4*)(y1 + j0) = a10;
        *(f32x4*)(y2 + j0) = a20; *(f32x4*)(y3 + j0) = a30;
    }
    if (j0 + 256 < NSAMP) {
        *(f32x4*)(y0 + j0 + 256) = a01; *(f32x4*)(y1 + j0 + 256) = a11;
        *(f32x4*)(y2 + j0 + 256) = a21; *(f32x4*)(y3 + j0 + 256) = a31;
    }
}
static inline size_t lds_gt4v3()
{
    return (size_t)(32 + GTDW + ((GTDW >> 5) << 2) + 16) * 4;
}

// ===========================================================================
// fir32b: per-channel 32x32x16 Toeplitz FIR, 2 j-tiles/wave (A reused 2x),
// pointer-stepped A with one-ahead prefetch, next-B prefetch before MFMA.
// Block = 8192 outputs (4 waves x 2048). phys16 swizzle (17-dword lane
// stride, conflict-free b32). Tile2 at +512 dwords -> phys +544.
//   desc: B idx = jb'+32n+kap+17-16s ; asc: jb'+32n+16s+kap  (r8-proven)
// ===========================================================================
template<int NC, bool ASC, bool ABSIN, bool DELAYED, bool GAIN>
__global__ __launch_bounds__(BLOCK)
void fir32b(const float* __restrict__ in, long instride,
            const unsigned short* __restrict__ TF,
            float* __restrict__ out,
            const int* __restrict__ delays, int chan0,
            const float* __restrict__ ratios, const float* __restrict__ eqloud)
{
    extern __shared__ float S[];
    unsigned* S32 = (unsigned*)S;
    const int c  = blockIdx.y;
    const int jb = blockIdx.x * 8192;
    const float* __restrict__ xin = in + (size_t)c * instride;
    const int o = ASC ? jb : (jb + 17 - 16 * (NC - 1));
    int d = 0;
    if (DELAYED) d = delays[chan0 + c];

    const int DW = 4088 + 8 * (NC - 1);
    for (int v = threadIdx.x; v < DW; v += BLOCK) {
        int p0 = o + 2 * v, p1 = p0 + 1;
        float a = 0.f, b = 0.f;
        if (DELAYED) {
            if (p0 >= 0 && p0 + d < NSAMP) a = xin[p0 + d];
            if (p1 >= 0 && p1 + d < NSAMP) b = xin[p1 + d];
        } else {
            if (p0 >= 0 && p0 < NSAMP) a = xin[p0];
            if (p1 >= 0 && p1 < NSAMP) b = xin[p1];
        }
        if (ABSIN) { a = fabsf(a); b = fabsf(b); }
        S32[16 + v + (v >> 4)] = (unsigned)f2bf(a) | ((unsigned)f2bf(b) << 16);
    }
    __syncthreads();

    const int lane = threadIdx.x & 63;
    const int w    = threadIdx.x >> 6;
    const int n    = lane & 31;
    const int h5   = lane >> 5;
    int v = 1024 * w + 16 * n + 4 * h5 + (ASC ? 0 : 8 * (NC - 1));

    const unsigned short* tp = TF + (size_t)c * NC * 512 + lane * 8;

    f32x16 acc0, acc1;
#pragma unroll
    for (int i = 0; i < 16; ++i) { acc0[i] = 0.f; acc1[i] = 0.f; }

    union Ub { float f[4]; bf16x8 v; };
    bf16x8 A = *(const bf16x8*)tp;
    Ub b0, b1;
    {
        int vp = 16 + v + (v >> 4);
        const float* sp = S + vp;
        b0.f[0]=sp[0];   b0.f[1]=sp[1];   b0.f[2]=sp[2];   b0.f[3]=sp[3];
        b1.f[0]=sp[544]; b1.f[1]=sp[545]; b1.f[2]=sp[546]; b1.f[3]=sp[547];
    }

#pragma unroll 1
    for (int s = 0; s < NC; ++s) {
        bf16x8 An = *(const bf16x8*)(tp + 512);   // one-past on last iter: discarded
        v += ASC ? 8 : -8;
        int vp = 16 + v + (v >> 4);               // guard absorbs final overrun
        const float* sp = S + vp;
        Ub n0, n1;
        n0.f[0]=sp[0];   n0.f[1]=sp[1];   n0.f[2]=sp[2];   n0.f[3]=sp[3];
        n1.f[0]=sp[544]; n1.f[1]=sp[545]; n1.f[2]=sp[546]; n1.f[3]=sp[547];
        acc0 = MFMA32(A, b0.v, acc0, 0, 0, 0);
        acc1 = MFMA32(A, b1.v, acc1, 0, 0, 0);
        A = An; b0 = n0; b1 = n1;
        tp += 512;
    }

    float* __restrict__ yo = out + (size_t)c * NSAMP;
    const int jb1 = jb + 2048 * w + 32 * n + 4 * h5;

    if (!GAIN) {
#pragma unroll
        for (int g = 0; g < 4; ++g) {
            int ja = jb1 + 8 * g, jbx = jb1 + 1024 + 8 * g;
            if (ja < NSAMP) {
                f32x4 st; st[0]=acc0[4*g]; st[1]=acc0[4*g+1]; st[2]=acc0[4*g+2]; st[3]=acc0[4*g+3];
                *(f32x4*)(yo + ja) = st;
            }
            if (jbx < NSAMP) {
                f32x4 st; st[0]=acc1[4*g]; st[1]=acc1[4*g+1]; st[2]=acc1[4*g+2]; st[3]=acc1[4*g+3];
                *(f32x4*)(yo + jbx) = st;
            }
        }
    } else {
        const float emax = exp10f(0.05f * (eqloud[c] - 100.0f));
        const float er   = fmaxf(ratios[c], -5.0f) - 1.0f;
#define GAINST(ACC, JV) { int j0 = (JV); if (j0 < NSAMP) {                  \
            f32x4 pv = *(f32x4*)(yo + j0);                                   \
            _Pragma("unroll")                                                \
            for (int q = 0; q < 4; ++q) {                                    \
                float env = ACC[4*g+q];                                      \
                float ecl = fminf(fmaxf(env, 1e-9f), emax);                  \
                float enr = fmaxf(ecl / emax, 1e-6f);                        \
                float gg  = fminf(powf(enr, er), 100.0f);                    \
                pv[q] *= gg;                                                 \
            }                                                                \
            *(f32x4*)(yo + j0) = pv; } }
#pragma unroll
        for (int g = 0; g < 4; ++g) {
            GAINST(acc0, jb1 + 8 * g)
            GAINST(acc1, jb1 + 1024 + 8 * g)
        }
#undef GAINST
    }
}
static inline size_t lds32b(int NC)
{
    int DW = 4088 + 8 * (NC - 1);
    return (size_t)(16 + DW + (DW >> 4) + 32) * 4;
}

// ===========================================================================
// VALU FIR (proven) — fused tail only
// ===========================================================================
__device__ __forceinline__ void group8d(const float (&LO)[8], const float (&HI)[8],
                                        float (&acc)[8], const f32x4 (&T)[2])
{
#pragma unroll
    for (int kp = 0; kp < 8; kp++) {
        const float hk = T[kp >> 2][kp & 3];
#pragma unroll
        for (int j = 0; j < 8; j++) {
            const int m = 8 + j - kp;
            const float w = (m < 8) ? LO[m] : HI[m - 8];
            acc[j] = fmaf(hk, w, acc[j]);
        }
    }
}

template<int Lpad>
__global__ __launch_bounds__(BLOCK)
void fir_blk(const float* __restrict__ in, const float* __restrict__ taps,
             float* __restrict__ out)
{
    extern __shared__ float s[];
    const int n0 = blockIdx.x * TILE;
    constexpr int E = TILE + Lpad - 1;
    for (int i = threadIdx.x; i < E; i += BLOCK) {
        int p = n0 - (Lpad - 1) + i;
        s[phys9(i + 9)] = (p >= 0 && p < NSAMP) ? in[p] : 0.f;
    }
    __syncthreads();

    const int t = threadIdx.x;
    constexpr int LB = Lpad / 8;
    const int B = 9 * (t + LB);
    const f32x4* tv = (const f32x4*)taps;

    float Ab[8], Bb[8], Cb[8];
    float acc[8] = {0,0,0,0,0,0,0,0};
#pragma unroll
    for (int m = 0; m < 8; m++) Ab[m] = s[B + m];
#pragma unroll
    for (int m = 0; m < 8; m++) Bb[m] = s[B + 9 + m];
    f32x4 TA[2], TB[2];
    TA[0] = tv[0]; TA[1] = tv[1];

    int Mb = B - 54;
    constexpr int NIT6 = Lpad / 48;
#pragma unroll 1
    for (int im = 0; im < NIT6; ++im) {
        const float* p = s + Mb;
#pragma unroll
        for (int m = 0; m < 8; m++) Cb[m] = p[45 + m];
        TB[0] = tv[2];  TB[1] = tv[3];
        group8d(Ab, Bb, acc, TA);
#pragma unroll
        for (int m = 0; m < 8; m++) Bb[m] = p[36 + m];
        TA[0] = tv[4];  TA[1] = tv[5];
        group8d(Cb, Ab, acc, TB);
#pragma unroll
        for (int m = 0; m < 8; m++) Ab[m] = p[27 + m];
        TB[0] = tv[6];  TB[1] = tv[7];
        group8d(Bb, Cb, acc, TA);
#pragma unroll
        for (int m = 0; m < 8; m++) Cb[m] = p[18 + m];
        TA[0] = tv[8];  TA[1] = tv[9];
        group8d(Ab, Bb, acc, TB);
#pragma unroll
        for (int m = 0; m < 8; m++) Bb[m] = p[9 + m];
        TB[0] = tv[10]; TB[1] = tv[11];
        group8d(Cb, Ab, acc, TA);
#pragma unroll
        for (int m = 0; m < 8; m++) Ab[m] = p[0 + m];
        TA[0] = tv[12]; TA[1] = tv[13];
        group8d(Bb, Cb, acc, TB);
        Mb -= 54;
        tv += 12;
    }

    const int nb = n0 + 8 * t;
#pragma unroll
    for (int j = 0; j < 8; j++)
        if (nb + j < NSAMP) out[nb + j] = acc[j];
}
static inline size_t lds_blk(int Lpad)
{
    int umax = TILE + Lpad + 8;
    return (size_t)(umax + (umax >> 3) + 16) * 4;
}

// ===========================================================================
// Small helpers
// ===========================================================================
__global__ void conv_self(const float* __restrict__ a, int astride, int La,
                          float* __restrict__ out, int ostride, int Mlen, int Mpad)
{
    extern __shared__ float s[];
    const int c = blockIdx.y;
    const float* __restrict__ ar = a + (long)c * astride;
    for (int i = threadIdx.x; i < La; i += blockDim.x) s[i] = ar[i];
    __syncthreads();
    int m = blockIdx.x * blockDim.x + threadIdx.x;
    float acc = 0.f;
    for (int k = 0; k < La; k++) {
        int mi = m - k;
        float bv = ((unsigned)mi < (unsigned)La) ? s[mi] : 0.f;
        acc = fmaf(s[k], bv, acc);
    }
    if (m < Mpad) out[(long)c * ostride + m] = (m < Mlen) ? acc : 0.f;
}

__global__ void conv_pair(const float* __restrict__ a, int astride, int La,
                          const float* __restrict__ b, int Lb,
                          float* __restrict__ out, int ostride, int Mlen, int Mpad)
{
    extern __shared__ float s[];
    const int c = blockIdx.y;
    for (int i = threadIdx.x; i < Lb; i += blockDim.x) s[i] = b[i];
    __syncthreads();
    int m = blockIdx.x * blockDim.x + threadIdx.x;
    float acc = 0.f;
    for (int k = 0; k < Lb; k++) {
        int mi = m - k;
        float av = ((unsigned)mi < (unsigned)La) ? a[(size_t)c * astride + mi] : 0.f;
        acc = fmaf(s[k], av, acc);
    }
    if (m < Mpad) out[(size_t)c * ostride + m] = (m < Mlen) ? acc : 0.f;
}

__global__ void pad_copy(const float* __restrict__ src, int L, int sstride,
                         float* __restrict__ dst, int Lpad)
{
    int c = blockIdx.y;
    int k = blockIdx.x * blockDim.x + threadIdx.x;
    if (k < Lpad) dst[(long)c * Lpad + k] = (k < L) ? src[(long)c * sstride + k] : 0.f;
}

__global__ void delay_copy(const float* __restrict__ a, float* __restrict__ b,
                           const int* __restrict__ delays)
{
    int c = blockIdx.y;
    int n = blockIdx.x * blockDim.x + threadIdx.x;
    if (n < NSAMP) {
        int q = n + delays[c];
        b[(long)c * NSAMP + n] = (q < NSAMP) ? a[(long)c * NSAMP + q] : 0.f;
    }
}

__global__ void reduce_coch(const float* __restrict__ b, float* __restrict__ coch)
{
    int n = blockIdx.x * blockDim.x + threadIdx.x;
    if (n < NSAMP) {
        float sum = 0.f;
        for (int c = 0; c < NCH; c++) sum += b[(long)c * NSAMP + n];
        coch[n] = sum * 0.31622776601683794f;
    }
}

extern "C" void kernel_launch(void* const* d_in, const int* in_sizes, int n_in,
                              void* d_out, int out_size, void* d_ws, size_t ws_size,
                              hipStream_t stream)
{
    const float* x       = (const float*)d_in[0];
    const float* src_fwd = (const float*)d_in[1];
    const float* src_bwd = (const float*)d_in[2];
    const float* lpf     = (const float*)d_in[3];
    const float* gtn     = (const float*)d_in[4];
    const float* hp      = (const float*)d_in[5];
    const float* clpf    = (const float*)d_in[6];
    const float* ratios  = (const float*)d_in[7];
    const float* eqloud  = (const float*)d_in[8];
    const int*   delays  = (const int*)d_in[9];
    float* out = (float*)d_out;

    float* ws = (float*)d_ws;
    const size_t CNs = (size_t)NCH * NSAMP;
    float* bufA  = ws;                            // C*N (y4, then env_f)
    float* bufB  = bufA + CNs;                    // C*N (pass_del -> coch_c)
    float* coch  = bufB + CNs;                    // N
    float* h2    = coch + NSAMP;                  // 28*2000
    float* h4    = h2 + (size_t)NCH * 2000;       // 28*LP_GT4
    float* h4f   = h4 + (size_t)NCH * LP_GT4;     // 28*LP_H4F
    float* hpP   = h4f + (size_t)NCH * LP_H4F;    // 24*LP_HP
    float* clpfP = hpP + (size_t)HPCH * LP_HP;    // 28*LP_ENV
    float* tb    = clpfP + (size_t)NCH * LP_ENV;  // LP_TB

    unsigned short* TF2  = (unsigned short*)(tb + LP_TB);   // 7*NC_GT*8192
    unsigned short* TFhp = TF2 + (size_t)7 * NC_GT * 8192;
    unsigned short* TFef = TFhp + (size_t)HPCH * NC_HP * 512 + 512;
    unsigned short* TFeb = TFef + (size_t)NCH * NC_EF * 512 + 512;
    // (+512 slack after each for harmless one-past A-prefetch)

    dim3 blk(BLOCK);

    // --- filter prep ---
    conv_self<<<dim3(8, NCH), blk, 1000 * 4, stream>>>(
        gtn, 1000, 1000, h2, 2000, 1999, 1999);
    conv_self<<<dim3(16, NCH), blk, 1999 * 4, stream>>>(
        h2, 2000, 1999, h4, LP_GT4, 3997, LP_GT4);
    conv_pair<<<dim3((LP_H4F + BLOCK - 1) / BLOCK, NCH), blk, 256 * 4, stream>>>(
        h4, LP_GT4, 3997, src_fwd, 256, h4f, LP_H4F, L_H4F, LP_H4F);
    conv_pair<<<dim3(2, 1), blk, 133 * 4, stream>>>(
        src_bwd, 0, 256, lpf, 133, tb, LP_TB, L_TB, LP_TB);
    pad_copy<<<dim3(4, HPCH), blk, 0, stream>>>(hp, 1000, 1000, hpP, LP_HP);
    pad_copy<<<dim3(8, NCH), blk, 0, stream>>>(clpf, 2000, 2000, clpfP, LP_ENV);

    prep_gt<<<dim3(NC_GT, NCH), dim3(64), 0, stream>>>(h4f, TF2);
    prep_frag32<<<dim3(NC_HP, HPCH), dim3(64), 0, stream>>>(hpP, LP_HP, TFhp, NC_HP, 0);
    prep_frag32<<<dim3(NC_EF, NCH), dim3(64), 0, stream>>>(clpfP, LP_ENV, TFef, NC_EF, 0);
    prep_frag32<<<dim3(NC_EB, NCH), dim3(64), 0, stream>>>(clpfP, LP_ENV, TFeb, NC_EB, 1);

    // --- signal path ---
    // y4 = (gammatone^4 (*) src_fwd) applied to x
    gt4_v3<<<dim3(108, 7), blk, lds_gt4v3(), stream>>>(x, TF2, bufA);

    delay_copy<<<dim3((NSAMP + BLOCK - 1) / BLOCK, 4), blk, 0, stream>>>(
        bufA, bufB, delays);

    // pass_del ch 4..27: HP with delay fetched at staging
    fir32b<NC_HP, false, false, true, false>
        <<<dim3(27, HPCH), blk, lds32b(NC_HP), stream>>>(
        bufA + 4 * (size_t)NSAMP, NSAMP, TFhp, bufB + 4 * (size_t)NSAMP,
        delays, 4, nullptr, nullptr);

    // env_f = causal fir(|pass_del|, clpf)
    fir32b<NC_EF, false, true, false, false>
        <<<dim3(27, NCH), blk, lds32b(NC_EF), stream>>>(
        bufB, NSAMP, TFef, bufA, nullptr, 0, nullptr, nullptr);

    // env = anti-causal fir(|env_f|, clpf) + fused recruitment gain
    fir32b<NC_EB, true, true, false, true>
        <<<dim3(27, NCH), blk, lds32b(NC_EB), stream>>>(
        bufA, NSAMP, TFeb, bufB, nullptr, 0, ratios, eqloud);

    reduce_coch<<<dim3((NSAMP + BLOCK - 1) / BLOCK), blk, 0, stream>>>(bufB, coch);

    // out = (lpf (*) src_bwd) (*) coch
    fir_blk<LP_TB><<<dim3(108, 1), blk, lds_blk(LP_TB), stream>>>(coch, tb, out);
}